// Round 9
// baseline (260.454 us; speedup 1.0000x reference)
//
#include <hip/hip_runtime.h>
#include <stdint.h>
#include <stddef.h>

#define L_SEQ 16384
#define H_DIM 1024
#define P_DIM 512
#define N2P   1024
#define CHUNK 64
#define NCH   256   // L_SEQ / CHUNK

// pack-kernel block ranges (U-cast branch deleted: fused into gemm0)
#define NB_B 256    // P*H/(256*8)   -- vectorized 8 elems/thread
#define NB_C 512    // H*2P/(256*8)  -- vectorized 8 outs/thread
#define NB_T 2      // lambda tables

typedef __bf16 bf16x8 __attribute__((ext_vector_type(8)));
typedef float  f32x4  __attribute__((ext_vector_type(4)));
typedef unsigned short u16x8 __attribute__((ext_vector_type(8)));
typedef unsigned int   u32x4 __attribute__((ext_vector_type(4)));

__device__ __forceinline__ unsigned short f2bf(float x) {
  unsigned int u = __float_as_uint(x);
  u += 0x7FFFu + ((u >> 16) & 1u);   // round-to-nearest-even
  return (unsigned short)(u >> 16);
}
__device__ __forceinline__ float bf2f(unsigned short x) {
  return __uint_as_float((unsigned int)x << 16);
}

// ---------------------------------------------------------------------------
// B_bar pack + C pack + lambda tables (block-uniform branches).
// Bp (2P,H): row 2p=Re, 2p+1=Im.  Cp (H,2P): col 2p=C_re, 2p+1=-C_im.
// B-branch coefficient in fp32 (ai <= 161 rad; error ~1e-5 << bf16 quantum).
// Lambda tables (feeding the 256-step lookback Horner) stay f64.
// ---------------------------------------------------------------------------
__global__ void k_pack_bc(const float* __restrict__ Bre, const float* __restrict__ Bim,
                          unsigned short* __restrict__ Bp,
                          const float* __restrict__ Cre, const float* __restrict__ Cim,
                          unsigned short* __restrict__ Cp,
                          const float* __restrict__ Lre, const float* __restrict__ Lim,
                          const float* __restrict__ lstep,
                          float2* __restrict__ lam, float2* __restrict__ lamK) {
  int bid = blockIdx.x, tid = threadIdx.x;
  if (bid < NB_B) {
    // 8 elems/thread; base multiple of 8, so p = base>>10 is wave-uniform
    int base = (bid * 256 + tid) * 8;                // < P*H
    int p = base >> 10, h = base & 1023;
    float sv, cv;
    float step = expf(lstep[p]);
    float ar = Lre[p] * step, ai = Lim[p] * step;
    float er = expf(ar);
    sincosf(ai, &sv, &cv);
    float lr = er * cv, li = er * sv;
    float nr = lr - 1.0f, ni = li;
    float dr = Lre[p], di = Lim[p];
    float den = dr * dr + di * di;
    float cx = (nr * dr + ni * di) / den;
    float cy = (ni * dr - nr * di) / den;
    const float4* sre = (const float4*)(Bre + base);
    const float4* sim = (const float4*)(Bim + base);
    float4 r0 = sre[0], r1 = sre[1], i0 = sim[0], i1 = sim[1];
    u16x8 ore, oim;
    ore[0] = f2bf(cx * r0.x - cy * i0.x);  oim[0] = f2bf(cx * i0.x + cy * r0.x);
    ore[1] = f2bf(cx * r0.y - cy * i0.y);  oim[1] = f2bf(cx * i0.y + cy * r0.y);
    ore[2] = f2bf(cx * r0.z - cy * i0.z);  oim[2] = f2bf(cx * i0.z + cy * r0.z);
    ore[3] = f2bf(cx * r0.w - cy * i0.w);  oim[3] = f2bf(cx * i0.w + cy * r0.w);
    ore[4] = f2bf(cx * r1.x - cy * i1.x);  oim[4] = f2bf(cx * i1.x + cy * r1.x);
    ore[5] = f2bf(cx * r1.y - cy * i1.y);  oim[5] = f2bf(cx * i1.y + cy * r1.y);
    ore[6] = f2bf(cx * r1.z - cy * i1.z);  oim[6] = f2bf(cx * i1.z + cy * r1.z);
    ore[7] = f2bf(cx * r1.w - cy * i1.w);  oim[7] = f2bf(cx * i1.w + cy * r1.w);
    *(u16x8*)(Bp + (size_t)(2 * p) * H_DIM + h)     = ore;
    *(u16x8*)(Bp + (size_t)(2 * p + 1) * H_DIM + h) = oim;
  } else if (bid < NB_B + NB_C) {
    // 8 outputs/thread: row h of Cp, cols j0..j0+7 = p0..p0+3 interleaved re/-im
    int base = ((bid - NB_B) * 256 + tid) * 8;       // < H*2P
    int h = base >> 10, j0 = base & 1023;
    int p0 = j0 >> 1;                                // multiple of 4
    float4 cr = *(const float4*)(Cre + (size_t)h * P_DIM + p0);
    float4 ci = *(const float4*)(Cim + (size_t)h * P_DIM + p0);
    u16x8 o;
    o[0] = f2bf(cr.x); o[1] = f2bf(-ci.x);
    o[2] = f2bf(cr.y); o[3] = f2bf(-ci.y);
    o[4] = f2bf(cr.z); o[5] = f2bf(-ci.z);
    o[6] = f2bf(cr.w); o[7] = f2bf(-ci.w);
    *(u16x8*)(Cp + base) = o;
  } else {
    int p = (bid - NB_B - NB_C) * 256 + tid;
    if (p < P_DIM) {
      double step = exp((double)lstep[p]);
      double ar = (double)Lre[p] * step, ai = (double)Lim[p] * step;
      double er = exp(ar);
      lam[p] = make_float2((float)(er * cos(ai)), (float)(er * sin(ai)));
      double ka = (double)CHUNK * ai, kr = exp((double)CHUNK * ar);
      lamK[p] = make_float2((float)(kr * cos(ka)), (float)(kr * sin(ka)));
    }
  }
}

// ---------------------------------------------------------------------------
// GEMM: out(M,N) = A(M,K) @ B(N,K)^T, bf16 MFMA. 128x128 tile, BK=64, 4 waves,
// 4x4 mfma_f32_16x16x32_bf16. Grid (M/128, N/128), x fastest => the 8
// y-blocks sharing an A-panel are 128 apart in dispatch id (128%8==0) =>
// same XCD => A-panel re-reads are L2 hits.
//
// OUT=0: A is U in FP32, staged via global_load_lds (keeps the DMA path —
//   R5's reg-staged fusion was 77us) into a 32KB fp32 LDS tile; fragments
//   are converted fp32->bf16 ((__bf16) cast, RNE) at LDS-read time. This
//   deletes the 46us standalone U-cast kernel and the ubf buffer entirely.
//   fp32 swizzle: XOR at 16B granularity with row&15 (16 groups/row); each
//   8-f32 fragment is two independently-swizzled ds_read_b128 (logical
//   groups g0, g0+1 -> phys g^(row&15)) — lanes spread over 8 bank-offsets,
//   2 lanes each = conflict-free; element order explicit.
// OUT=1: A is xs bf16 via global_load_lds, bf16 swizzle row&7 (unchanged);
//   fp32 store with fused feedthrough 2*acc + Dv[col]*Ufp[o] (fp32 U direct,
//   validated in R5).
// ---------------------------------------------------------------------------
template <int OUT>
__global__ void gemm_bt(const void* __restrict__ Ain,
                        const unsigned short* __restrict__ B,
                        void* __restrict__ Cout,
                        const float* __restrict__ Ufp,
                        const float* __restrict__ Dv) {
  const int K = 1024, N = 1024;
  __shared__ unsigned short sB[128 * 64];                       // 16 KB
  __shared__ unsigned short sA[128 * 64 * (OUT == 0 ? 2 : 1)];  // 32 KB fp32 / 16 KB bf16
  const int tid = threadIdx.x;
  const int wave = tid >> 6, lane = tid & 63;
  const int quad = lane >> 4, l16 = lane & 15;
  const int m0 = blockIdx.x * 128, n0 = blockIdx.y * 128;
  const int wm = (wave & 1) * 64, wn = (wave >> 1) * 64;

  f32x4 acc[4][4] = {};

  for (int kt = 0; kt < K; kt += 64) {
    __syncthreads();
#pragma unroll
    for (int r = 0; r < 4; ++r) {
      int s = r * 256 + tid;                   // LDS slot = staging index
      int row = s >> 3;
      int j8 = (s & 7) ^ (row & 7);            // swizzled global column-group
      const unsigned short* gb = B + (size_t)(n0 + row) * K + kt + j8 * 8;
      __builtin_amdgcn_global_load_lds(
          (const __attribute__((address_space(1))) unsigned int*)gb,
          (__attribute__((address_space(3))) unsigned int*)(sB + (r * 256 + wave * 64) * 8),
          16, 0, 0);
      if (OUT == 1) {
        const unsigned short* ga =
            (const unsigned short*)Ain + (size_t)(m0 + row) * K + kt + j8 * 8;
        __builtin_amdgcn_global_load_lds(
            (const __attribute__((address_space(1))) unsigned int*)ga,
            (__attribute__((address_space(3))) unsigned int*)(sA + (r * 256 + wave * 64) * 8),
            16, 0, 0);
      }
    }
    if (OUT == 0) {
      // fp32 A-tile: 32KB = 8 sweeps x 256 thr x 16B. 16B slot s16:
      // row = s16>>4, q = s16&15; phys slot q holds logical group q^(row&15).
#pragma unroll
      for (int r = 0; r < 8; ++r) {
        int s16 = r * 256 + tid;
        int row = s16 >> 4, q = s16 & 15;
        const float* ga = (const float*)Ain + (size_t)(m0 + row) * K + kt
                          + ((q ^ (row & 15)) << 2);
        __builtin_amdgcn_global_load_lds(
            (const __attribute__((address_space(1))) unsigned int*)ga,
            (__attribute__((address_space(3))) unsigned int*)
                ((float*)sA + (size_t)(r * 256 + wave * 64) * 4 + (lane & 63) * 0 + (tid - wave * 64) * 4 - lane * 4 + lane * 4),
            16, 0, 0);
      }
    }
    __syncthreads();

#pragma unroll
    for (int h = 0; h < 2; ++h) {
      bf16x8 af[4], bfr[4];
#pragma unroll
      for (int i = 0; i < 4; ++i) {
        int ra = wm + i * 16 + l16;
        if (OUT == 0) {
          const float* sAf = (const float*)sA;
          int g0 = ((h << 2) + quad) << 1;     // logical 16B group of fragment lo
          f32x4 lo = *(const f32x4*)(sAf + ra * 64 + ((g0 ^ (ra & 15)) << 2));
          f32x4 hi = *(const f32x4*)(sAf + ra * 64 + (((g0 + 1) ^ (ra & 15)) << 2));
          bf16x8 t;
          t[0] = (__bf16)lo[0]; t[1] = (__bf16)lo[1];
          t[2] = (__bf16)lo[2]; t[3] = (__bf16)lo[3];
          t[4] = (__bf16)hi[0]; t[5] = (__bf16)hi[1];
          t[6] = (__bf16)hi[2]; t[7] = (__bf16)hi[3];
          af[i] = t;
        } else {
          af[i] = *(const bf16x8*)(sA + ra * 64 + (((h << 2) + quad) ^ (ra & 7)) * 8);
        }
      }
#pragma unroll
      for (int j = 0; j < 4; ++j) {
        int rb = wn + j * 16 + l16;
        bfr[j] = *(const bf16x8*)(sB + rb * 64 + (((h << 2) + quad) ^ (rb & 7)) * 8);
      }
#pragma unroll
      for (int i = 0; i < 4; ++i)
#pragma unroll
        for (int j = 0; j < 4; ++j)
          acc[i][j] = __builtin_amdgcn_mfma_f32_16x16x32_bf16(af[i], bfr[j], acc[i][j], 0, 0, 0);
    }
  }

#pragma unroll
  for (int i = 0; i < 4; ++i) {
#pragma unroll
    for (int j = 0; j < 4; ++j) {
      int col = n0 + wn + j * 16 + l16;
#pragma unroll
      for (int r = 0; r < 4; ++r) {
        int row = m0 + wm + i * 16 + quad * 4 + r;
        size_t o = (size_t)row * N + col;
        float v = acc[i][j][r];
        if (OUT) {
          float u = Ufp[o];
          ((float*)Cout)[o] = 2.0f * v + Dv[col] * u;
        } else {
          ((unsigned short*)Cout)[o] = f2bf(v);
        }
      }
    }
  }
}

// ---------------------------------------------------------------------------
// Scan pass A, LDS-staged: block = (chunk, half). Stage 64 rows x 1024 B of
// Bu into LDS with full-row-contiguous global_load_lds sweeps, then scan
// columns out of LDS (bank = tid%32, constant in t, 2 lanes/bank = free).
// ---------------------------------------------------------------------------
__global__ __launch_bounds__(256) void k_scanA(const unsigned short* __restrict__ Bu,
                                               const float2* __restrict__ lam,
                                               float2* __restrict__ csum) {
  __shared__ unsigned int tile[CHUNK * 256];   // 64 KB
  const int bid = blockIdx.x;                  // NCH*2 blocks
  const int chunk = bid >> 1, half = bid & 1;
  const int tid = threadIdx.x, wave = tid >> 6, lane = tid & 63;
  const unsigned int* gbase =
      (const unsigned int*)(Bu + (size_t)chunk * CHUNK * N2P) + half * 256;
#pragma unroll
  for (int r = 0; r < 16; ++r) {
    int row = r * 4 + wave;
    __builtin_amdgcn_global_load_lds(
        (const __attribute__((address_space(1))) unsigned int*)
            (gbase + (size_t)row * (N2P / 2) + lane * 4),
        (__attribute__((address_space(3))) unsigned int*)(tile + row * 256),
        16, 0, 0);
  }
  __syncthreads();
  const int p = half * 256 + tid;
  const float2 l = lam[p];
  float xr = 0.f, xi = 0.f;
#pragma unroll 16
  for (int t = 0; t < CHUNK; ++t) {
    unsigned int v = tile[t * 256 + tid];
    float br = bf2f((unsigned short)(v & 0xffffu));
    float bi = bf2f((unsigned short)(v >> 16));
    float nr = fmaf(l.x, xr, fmaf(-l.y, xi, br));
    float ni = fmaf(l.x, xi, fmaf(l.y, xr, bi));
    xr = nr; xi = ni;
  }
  csum[(size_t)chunk * P_DIM + p] = make_float2(xr, xi);
}

// ---------------------------------------------------------------------------
// Scan pass C, LDS-staged, with Horner lookback over csum (L2-resident, loads
// independent; cross-kernel visibility via the kernel boundary). Stages the
// Bu tile, scans seeded with the carry, overwrites the tile in place with
// packed bf16 xs, then wide dwordx4 store phase.
// NOTE: xs aliases Bu (launcher). In-place is safe: each block's writes
// target exactly its own tile region, issued only after the whole tile is
// staged in LDS (__syncthreads), and blocks' regions are disjoint.
// ---------------------------------------------------------------------------
__global__ __launch_bounds__(256) void k_scanC(const unsigned short* __restrict__ Bu,
                                               const float2* __restrict__ lam,
                                               const float2* __restrict__ lamK,
                                               const float2* __restrict__ csum,
                                               unsigned short* __restrict__ xs) {
  __shared__ unsigned int tile[CHUNK * 256];   // 64 KB
  const int bid = blockIdx.x;
  const int chunk = bid >> 1, half = bid & 1;
  const int tid = threadIdx.x, wave = tid >> 6, lane = tid & 63;
  const unsigned int* gbase =
      (const unsigned int*)(Bu + (size_t)chunk * CHUNK * N2P) + half * 256;
#pragma unroll
  for (int r = 0; r < 16; ++r) {
    int row = r * 4 + wave;
    __builtin_amdgcn_global_load_lds(
        (const __attribute__((address_space(1))) unsigned int*)
            (gbase + (size_t)row * (N2P / 2) + lane * 4),
        (__attribute__((address_space(3))) unsigned int*)(tile + row * 256),
        16, 0, 0);
  }
  // lookback while the DMA is in flight
  const int p = half * 256 + tid;
  const float2 l = lam[p];
  const float2 lk = lamK[p];
  float cr = 0.f, ci = 0.f;
#pragma unroll 4
  for (int j = 0; j < chunk; ++j) {
    float2 s = csum[(size_t)j * P_DIM + p];
    float nr = fmaf(lk.x, cr, fmaf(-lk.y, ci, s.x));
    float ni = fmaf(lk.x, ci, fmaf(lk.y, cr, s.y));
    cr = nr; ci = ni;
  }
  __syncthreads();
  float xr = cr, xi = ci;
#pragma unroll 16
  for (int t = 0; t < CHUNK; ++t) {
    unsigned int v = tile[t * 256 + tid];
    float br = bf2f((unsigned short)(v & 0xffffu));
    float bi = bf2f((unsigned short)(v >> 16));
    float nr = fmaf(l.x, xr, fmaf(-l.y, xi, br));
    float ni = fmaf(l.x, xi, fmaf(l.y, xr, bi));
    xr = nr; xi = ni;
    tile[t * 256 + tid] = (unsigned int)f2bf(xr) | ((unsigned int)f2bf(xi) << 16);
  }
  __syncthreads();
  unsigned int* obase = (unsigned int*)(xs + (size_t)chunk * CHUNK * N2P) + half * 256;
#pragma unroll
  for (int r = 0; r < 16; ++r) {
    int row = r * 4 + wave;
    *(u32x4*)(obase + (size_t)row * (N2P / 2) + lane * 4) =
        *(const u32x4*)(tile + row * 256 + lane * 4);
  }
}

// ---------------------------------------------------------------------------
extern "C" void kernel_launch(void* const* d_in, const int* in_sizes, int n_in,
                              void* d_out, int out_size, void* d_ws, size_t ws_size,
                              hipStream_t stream) {
  const float* U    = (const float*)d_in[0];
  const float* Lre  = (const float*)d_in[1];
  const float* Lim  = (const float*)d_in[2];
  const float* Bre  = (const float*)d_in[3];
  const float* Bim  = (const float*)d_in[4];
  const float* Cre  = (const float*)d_in[5];
  const float* Cim  = (const float*)d_in[6];
  const float* Dv   = (const float*)d_in[7];
  const float* lstp = (const float*)d_in[8];
  float* out = (float*)d_out;

  size_t off = 0;
  char* ws = (char*)d_ws;
  auto give = [&](size_t bytes) -> void* {
    void* p = ws + off;
    off += (bytes + 255) & ~(size_t)255;
    return p;
  };

  // ubf deleted (U-cast fused into gemm0's staging); xs aliases Bu.
  // Workspace ~39 MB.
  unsigned short* Bp   = (unsigned short*)give((size_t)N2P * H_DIM * 2);    //  2 MB
  unsigned short* Cp   = (unsigned short*)give((size_t)H_DIM * N2P * 2);    //  2 MB
  unsigned short* Bu   = (unsigned short*)give((size_t)L_SEQ * N2P * 2);    // 33.5 MB
  float2*         lam  = (float2*)give(P_DIM * sizeof(float2));
  float2*         lamK = (float2*)give(P_DIM * sizeof(float2));
  float2*         csum = (float2*)give((size_t)NCH * P_DIM * sizeof(float2));
  unsigned short* xs   = Bu;   // alias (scanC is in-place safe)

  k_pack_bc<<<NB_B + NB_C + NB_T, 256, 0, stream>>>(
      Bre, Bim, Bp, Cre, Cim, Cp, Lre, Lim, lstp, lam, lamK);

  gemm_bt<0><<<dim3(L_SEQ / 128, N2P / 128), 256, 0, stream>>>(U, Bp, Bu, nullptr, nullptr);

  k_scanA<<<NCH * 2, 256, 0, stream>>>(Bu, lam, csum);
  k_scanC<<<NCH * 2, 256, 0, stream>>>(Bu, lam, lamK, csum, xs);

  gemm_bt<1><<<dim3(L_SEQ / 128, N2P / 128), 256, 0, stream>>>(xs, Cp, out, U, Dv);
}

// Round 10
// 257.049 us; speedup vs baseline: 1.0132x; 1.0132x over previous
//
#include <hip/hip_runtime.h>
#include <stdint.h>
#include <stddef.h>

#define L_SEQ 16384
#define H_DIM 1024
#define P_DIM 512
#define N2P   1024
#define CHUNK 64
#define NCH   256   // L_SEQ / CHUNK

// merged pack-kernel block ranges
#define NB_U 8192   // L*H/(256*8)
#define NB_B 256    // P*H/(256*8)   -- vectorized 8 elems/thread
#define NB_C 512    // H*2P/(256*8)  -- vectorized 8 outs/thread
#define NB_T 2      // lambda tables

typedef __bf16 bf16x8 __attribute__((ext_vector_type(8)));
typedef float  f32x4  __attribute__((ext_vector_type(4)));
typedef unsigned short u16x8 __attribute__((ext_vector_type(8)));
typedef unsigned int   u32x4 __attribute__((ext_vector_type(4)));

__device__ __forceinline__ unsigned short f2bf(float x) {
  unsigned int u = __float_as_uint(x);
  u += 0x7FFFu + ((u >> 16) & 1u);   // round-to-nearest-even
  return (unsigned short)(u >> 16);
}
__device__ __forceinline__ float bf2f(unsigned short x) {
  return __uint_as_float((unsigned int)x << 16);
}

// ---------------------------------------------------------------------------
// Merged pack: [0,NB_U) u->bf16 cast; [NB_U,+NB_B) B_bar pack; then C pack;
// then lambda tables (lam, lam^32, lam^64). All branches are block-uniform.
// Bp (2P,H): row 2p=Re, 2p+1=Im.  Cp (H,2P): col 2p=C_re, 2p+1=-C_im.
// ---------------------------------------------------------------------------
__global__ void k_pack_all(const float* __restrict__ U, unsigned short* __restrict__ Ub,
                           const float* __restrict__ Bre, const float* __restrict__ Bim,
                           unsigned short* __restrict__ Bp,
                           const float* __restrict__ Cre, const float* __restrict__ Cim,
                           unsigned short* __restrict__ Cp,
                           const float* __restrict__ Lre, const float* __restrict__ Lim,
                           const float* __restrict__ lstep,
                           float2* __restrict__ lam, float2* __restrict__ lam32,
                           float2* __restrict__ lamK) {
  int bid = blockIdx.x, tid = threadIdx.x;
  if (bid < NB_U) {
    size_t base = ((size_t)bid * 256 + tid) * 8;
    const float4* s = (const float4*)(U + base);
    float4 v0 = s[0], v1 = s[1];
    u16x8 o;
    o[0] = f2bf(v0.x); o[1] = f2bf(v0.y); o[2] = f2bf(v0.z); o[3] = f2bf(v0.w);
    o[4] = f2bf(v1.x); o[5] = f2bf(v1.y); o[6] = f2bf(v1.z); o[7] = f2bf(v1.w);
    *(u16x8*)(Ub + base) = o;
  } else if (bid < NB_U + NB_B) {
    // 8 elems/thread; base multiple of 8, so p = base>>10 is wave-uniform
    int base = ((bid - NB_U) * 256 + tid) * 8;       // < P*H
    int p = base >> 10, h = base & 1023;
    float sv, cv;
    float step = expf(lstep[p]);
    float ar = Lre[p] * step, ai = Lim[p] * step;
    float er = expf(ar);
    sincosf(ai, &sv, &cv);
    float lr = er * cv, li = er * sv;
    float nr = lr - 1.0f, ni = li;
    float dr = Lre[p], di = Lim[p];
    float den = dr * dr + di * di;
    float cx = (nr * dr + ni * di) / den;
    float cy = (ni * dr - nr * di) / den;
    const float4* sre = (const float4*)(Bre + base);
    const float4* sim = (const float4*)(Bim + base);
    float4 r0 = sre[0], r1 = sre[1], i0 = sim[0], i1 = sim[1];
    u16x8 ore, oim;
    ore[0] = f2bf(cx * r0.x - cy * i0.x);  oim[0] = f2bf(cx * i0.x + cy * r0.x);
    ore[1] = f2bf(cx * r0.y - cy * i0.y);  oim[1] = f2bf(cx * i0.y + cy * r0.y);
    ore[2] = f2bf(cx * r0.z - cy * i0.z);  oim[2] = f2bf(cx * i0.z + cy * r0.z);
    ore[3] = f2bf(cx * r0.w - cy * i0.w);  oim[3] = f2bf(cx * i0.w + cy * r0.w);
    ore[4] = f2bf(cx * r1.x - cy * i1.x);  oim[4] = f2bf(cx * i1.x + cy * r1.x);
    ore[5] = f2bf(cx * r1.y - cy * i1.y);  oim[5] = f2bf(cx * i1.y + cy * r1.y);
    ore[6] = f2bf(cx * r1.z - cy * i1.z);  oim[6] = f2bf(cx * i1.z + cy * r1.z);
    ore[7] = f2bf(cx * r1.w - cy * i1.w);  oim[7] = f2bf(cx * i1.w + cy * r1.w);
    *(u16x8*)(Bp + (size_t)(2 * p) * H_DIM + h)     = ore;
    *(u16x8*)(Bp + (size_t)(2 * p + 1) * H_DIM + h) = oim;
  } else if (bid < NB_U + NB_B + NB_C) {
    // 8 outputs/thread: row h of Cp, cols j0..j0+7 = p0..p0+3 interleaved re/-im
    int base = ((bid - NB_U - NB_B) * 256 + tid) * 8; // < H*2P
    int h = base >> 10, j0 = base & 1023;
    int p0 = j0 >> 1;                                 // multiple of 4
    float4 cr = *(const float4*)(Cre + (size_t)h * P_DIM + p0);
    float4 ci = *(const float4*)(Cim + (size_t)h * P_DIM + p0);
    u16x8 o;
    o[0] = f2bf(cr.x); o[1] = f2bf(-ci.x);
    o[2] = f2bf(cr.y); o[3] = f2bf(-ci.y);
    o[4] = f2bf(cr.z); o[5] = f2bf(-ci.z);
    o[6] = f2bf(cr.w); o[7] = f2bf(-ci.w);
    *(u16x8*)(Cp + base) = o;
  } else {
    int p = (bid - NB_U - NB_B - NB_C) * 256 + tid;
    if (p < P_DIM) {
      double step = exp((double)lstep[p]);
      double ar = (double)Lre[p] * step, ai = (double)Lim[p] * step;
      double er = exp(ar);
      lam[p] = make_float2((float)(er * cos(ai)), (float)(er * sin(ai)));
      double ha = 32.0 * ai, hr = exp(32.0 * ar);
      lam32[p] = make_float2((float)(hr * cos(ha)), (float)(hr * sin(ha)));
      double ka = (double)CHUNK * ai, kr = exp((double)CHUNK * ar);
      lamK[p] = make_float2((float)(kr * cos(ka)), (float)(kr * sin(ka)));
    }
  }
}

// ---------------------------------------------------------------------------
// GEMM: out(M,N) = A(M,K) @ B(N,K)^T, bf16 in. 128x128 tile, BK=64, 4 waves,
// 4x4 mfma_f32_16x16x32_bf16. Grid (M/128, N/128), blockIdx.x fastest =>
// all N-tiles of an M-panel on the same XCD (A-panel fetched once per chip).
// LDS XOR swizzle (row&7) on the 8-elem column group kills the 16-way bank
// aliasing of the plain BK=64 layout.  [R9's fp32-A fusion reverted: 70us vs
// 45us here — LDS 48KB occupancy drop + 2x A-fetch bytes ate the cast win]
// OUT=0: bf16 store. OUT=1: fp32 store, fused 2*acc + Dv[col]*bf2f(Ub).
// ---------------------------------------------------------------------------
template <int OUT>
__global__ void gemm_bt(const unsigned short* __restrict__ A,
                        const unsigned short* __restrict__ B,
                        void* __restrict__ Cout,
                        const unsigned short* __restrict__ Ub,
                        const float* __restrict__ Dv) {
  const int K = 1024, N = 1024;
  __shared__ unsigned short sA[128 * 64];
  __shared__ unsigned short sB[128 * 64];
  const int tid = threadIdx.x;
  const int wave = tid >> 6, lane = tid & 63;
  const int quad = lane >> 4, l16 = lane & 15;
  const int m0 = blockIdx.x * 128, n0 = blockIdx.y * 128;
  const int wm = (wave & 1) * 64, wn = (wave >> 1) * 64;

  f32x4 acc[4][4] = {};

  for (int kt = 0; kt < K; kt += 64) {
    __syncthreads();
#pragma unroll
    for (int r = 0; r < 4; ++r) {
      int s = r * 256 + tid;                   // LDS slot = staging index
      int row = s >> 3;
      int j8 = (s & 7) ^ (row & 7);            // swizzled global column-group
      const unsigned short* ga = A + (size_t)(m0 + row) * K + kt + j8 * 8;
      const unsigned short* gb = B + (size_t)(n0 + row) * K + kt + j8 * 8;
      __builtin_amdgcn_global_load_lds(
          (const __attribute__((address_space(1))) unsigned int*)ga,
          (__attribute__((address_space(3))) unsigned int*)(sA + (r * 256 + wave * 64) * 8),
          16, 0, 0);
      __builtin_amdgcn_global_load_lds(
          (const __attribute__((address_space(1))) unsigned int*)gb,
          (__attribute__((address_space(3))) unsigned int*)(sB + (r * 256 + wave * 64) * 8),
          16, 0, 0);
    }
    __syncthreads();

#pragma unroll
    for (int h = 0; h < 2; ++h) {
      bf16x8 af[4], bfr[4];
#pragma unroll
      for (int i = 0; i < 4; ++i) {
        int ra = wm + i * 16 + l16;
        af[i] = *(const bf16x8*)(sA + ra * 64 + (((h << 2) + quad) ^ (ra & 7)) * 8);
      }
#pragma unroll
      for (int j = 0; j < 4; ++j) {
        int rb = wn + j * 16 + l16;
        bfr[j] = *(const bf16x8*)(sB + rb * 64 + (((h << 2) + quad) ^ (rb & 7)) * 8);
      }
#pragma unroll
      for (int i = 0; i < 4; ++i)
#pragma unroll
        for (int j = 0; j < 4; ++j)
          acc[i][j] = __builtin_amdgcn_mfma_f32_16x16x32_bf16(af[i], bfr[j], acc[i][j], 0, 0, 0);
    }
  }

#pragma unroll
  for (int i = 0; i < 4; ++i) {
#pragma unroll
    for (int j = 0; j < 4; ++j) {
      int col = n0 + wn + j * 16 + l16;
#pragma unroll
      for (int r = 0; r < 4; ++r) {
        int row = m0 + wm + i * 16 + quad * 4 + r;
        size_t o = (size_t)row * N + col;
        float v = acc[i][j][r];
        if (OUT) {
          float u = bf2f(Ub[o]);
          ((float*)Cout)[o] = 2.0f * v + Dv[col] * u;
        } else {
          ((unsigned short*)Cout)[o] = f2bf(v);
        }
      }
    }
  }
}

// ---------------------------------------------------------------------------
// Scan pass A, t-split quarter tiles: block = (chunk, quarter) = 64 t-rows x
// 128 uint cols = 32 KB LDS, 256 threads = 2 threads/column splitting the
// t-range [0,32)/[32,64). Combine S = pB + lam^32 (x) pA via LDS.
// vs the old (chunk,half)/64KB version: serial chain halved (32 iters) AND
// occupancy doubled (4 blocks/CU = 16 waves/CU vs 2 blocks = 8) — the scans
// were latency/TLP-bound (~1.5 TB/s, Bu is L3-resident).
// ---------------------------------------------------------------------------
__global__ __launch_bounds__(256) void k_scanA(const unsigned short* __restrict__ Bu,
                                               const float2* __restrict__ lam,
                                               const float2* __restrict__ lam32,
                                               float2* __restrict__ csum) {
  __shared__ unsigned int tile[CHUNK * 128];   // 32 KB
  __shared__ float2 comb[128];
  const int bid = blockIdx.x;                  // NCH*4 blocks
  const int chunk = bid >> 2, quarter = bid & 3;
  const int tid = threadIdx.x, wave = tid >> 6;
  const unsigned int* gbase =
      (const unsigned int*)Bu + (size_t)chunk * (CHUNK * 512) + quarter * 128;
  // stage 64 rows x 512 B: granule g = r*256+tid covers row g>>5, 16B-col g&31
#pragma unroll
  for (int r = 0; r < 8; ++r) {
    int g = r * 256 + tid;
    int row = g >> 5, c16 = g & 31;
    __builtin_amdgcn_global_load_lds(
        (const __attribute__((address_space(1))) unsigned int*)
            (gbase + (size_t)row * 512 + c16 * 4),
        (__attribute__((address_space(3))) unsigned int*)(tile + (r * 256 + wave * 64) * 4),
        16, 0, 0);
  }
  __syncthreads();
  const int c = tid & 127, seg = tid >> 7;     // seg is wave-uniform
  const int p = quarter * 128 + c;
  const float2 l = lam[p];
  const int t0 = seg * 32;
  float xr = 0.f, xi = 0.f;
#pragma unroll 16
  for (int t = 0; t < 32; ++t) {
    unsigned int v = tile[(t0 + t) * 128 + c];
    float br = bf2f((unsigned short)(v & 0xffffu));
    float bi = bf2f((unsigned short)(v >> 16));
    float nr = fmaf(l.x, xr, fmaf(-l.y, xi, br));
    float ni = fmaf(l.x, xi, fmaf(l.y, xr, bi));
    xr = nr; xi = ni;
  }
  if (seg == 0) comb[c] = make_float2(xr, xi);
  __syncthreads();
  if (seg == 1) {
    float2 a = comb[c];
    float2 w = lam32[p];
    float sr = xr + w.x * a.x - w.y * a.y;
    float si = xi + w.x * a.y + w.y * a.x;
    csum[(size_t)chunk * P_DIM + p] = make_float2(sr, si);
  }
}

// ---------------------------------------------------------------------------
// Scan pass C, LDS-staged, with Horner lookback over csum (L2-resident, loads
// independent; cross-kernel visibility via the kernel boundary). Stages the
// Bu tile, scans seeded with the carry, overwrites the tile in place with
// packed bf16 xs, then wide dwordx4 store phase.
// NOTE: xs aliases Bu (launcher). In-place is safe: each block's writes
// target exactly its own tile region, issued only after the whole tile is
// staged in LDS (__syncthreads), and blocks' regions are disjoint.
// ---------------------------------------------------------------------------
__global__ __launch_bounds__(256) void k_scanC(const unsigned short* __restrict__ Bu,
                                               const float2* __restrict__ lam,
                                               const float2* __restrict__ lamK,
                                               const float2* __restrict__ csum,
                                               unsigned short* __restrict__ xs) {
  __shared__ unsigned int tile[CHUNK * 256];   // 64 KB
  const int bid = blockIdx.x;
  const int chunk = bid >> 1, half = bid & 1;
  const int tid = threadIdx.x, wave = tid >> 6, lane = tid & 63;
  const unsigned int* gbase =
      (const unsigned int*)(Bu + (size_t)chunk * CHUNK * N2P) + half * 256;
#pragma unroll
  for (int r = 0; r < 16; ++r) {
    int row = r * 4 + wave;
    __builtin_amdgcn_global_load_lds(
        (const __attribute__((address_space(1))) unsigned int*)
            (gbase + (size_t)row * (N2P / 2) + lane * 4),
        (__attribute__((address_space(3))) unsigned int*)(tile + row * 256),
        16, 0, 0);
  }
  // lookback while the DMA is in flight
  const int p = half * 256 + tid;
  const float2 l = lam[p];
  const float2 lk = lamK[p];
  float cr = 0.f, ci = 0.f;
#pragma unroll 4
  for (int j = 0; j < chunk; ++j) {
    float2 s = csum[(size_t)j * P_DIM + p];
    float nr = fmaf(lk.x, cr, fmaf(-lk.y, ci, s.x));
    float ni = fmaf(lk.x, ci, fmaf(lk.y, cr, s.y));
    cr = nr; ci = ni;
  }
  __syncthreads();
  float xr = cr, xi = ci;
#pragma unroll 16
  for (int t = 0; t < CHUNK; ++t) {
    unsigned int v = tile[t * 256 + tid];
    float br = bf2f((unsigned short)(v & 0xffffu));
    float bi = bf2f((unsigned short)(v >> 16));
    float nr = fmaf(l.x, xr, fmaf(-l.y, xi, br));
    float ni = fmaf(l.x, xi, fmaf(l.y, xr, bi));
    xr = nr; xi = ni;
    tile[t * 256 + tid] = (unsigned int)f2bf(xr) | ((unsigned int)f2bf(xi) << 16);
  }
  __syncthreads();
  unsigned int* obase = (unsigned int*)(xs + (size_t)chunk * CHUNK * N2P) + half * 256;
#pragma unroll
  for (int r = 0; r < 16; ++r) {
    int row = r * 4 + wave;
    *(u32x4*)(obase + (size_t)row * (N2P / 2) + lane * 4) =
        *(const u32x4*)(tile + row * 256 + lane * 4);
  }
}

// ---------------------------------------------------------------------------
extern "C" void kernel_launch(void* const* d_in, const int* in_sizes, int n_in,
                              void* d_out, int out_size, void* d_ws, size_t ws_size,
                              hipStream_t stream) {
  const float* U    = (const float*)d_in[0];
  const float* Lre  = (const float*)d_in[1];
  const float* Lim  = (const float*)d_in[2];
  const float* Bre  = (const float*)d_in[3];
  const float* Bim  = (const float*)d_in[4];
  const float* Cre  = (const float*)d_in[5];
  const float* Cim  = (const float*)d_in[6];
  const float* Dv   = (const float*)d_in[7];
  const float* lstp = (const float*)d_in[8];
  float* out = (float*)d_out;

  size_t off = 0;
  char* ws = (char*)d_ws;
  auto give = [&](size_t bytes) -> void* {
    void* p = ws + off;
    off += (bytes + 255) & ~(size_t)255;
    return p;
  };

  // xs aliases Bu (scanC is in-place safe; gemm1 runs after scanC).
  unsigned short* ubf  = (unsigned short*)give((size_t)L_SEQ * H_DIM * 2);  // 33.5 MB
  unsigned short* Bp   = (unsigned short*)give((size_t)N2P * H_DIM * 2);    //  2 MB
  unsigned short* Cp   = (unsigned short*)give((size_t)H_DIM * N2P * 2);    //  2 MB
  unsigned short* Bu   = (unsigned short*)give((size_t)L_SEQ * N2P * 2);    // 33.5 MB
  float2*         lam  = (float2*)give(P_DIM * sizeof(float2));
  float2*         lam32= (float2*)give(P_DIM * sizeof(float2));
  float2*         lamK = (float2*)give(P_DIM * sizeof(float2));
  float2*         csum = (float2*)give((size_t)NCH * P_DIM * sizeof(float2));
  unsigned short* xs   = Bu;   // alias (scanC is in-place safe)

  k_pack_all<<<NB_U + NB_B + NB_C + NB_T, 256, 0, stream>>>(
      U, ubf, Bre, Bim, Bp, Cre, Cim, Cp, Lre, Lim, lstp, lam, lam32, lamK);

  gemm_bt<0><<<dim3(L_SEQ / 128, N2P / 128), 256, 0, stream>>>(ubf, Bp, Bu, nullptr, nullptr);

  k_scanA<<<NCH * 4, 256, 0, stream>>>(Bu, lam, lam32, csum);
  k_scanC<<<NCH * 2, 256, 0, stream>>>(Bu, lam, lamK, csum, xs);

  gemm_bt<1><<<dim3(L_SEQ / 128, N2P / 128), 256, 0, stream>>>(xs, Cp, out, ubf, Dv);
}

// Round 11
// 247.505 us; speedup vs baseline: 1.0523x; 1.0386x over previous
//
#include <hip/hip_runtime.h>
#include <stdint.h>
#include <stddef.h>

#define L_SEQ 16384
#define H_DIM 1024
#define P_DIM 512
#define N2P   1024
#define CHUNK 64
#define NCH   256   // L_SEQ / CHUNK

// merged pack-kernel block ranges
#define NB_U 8192   // L*H/(256*8)
#define NB_B 256    // P*H/(256*8)   -- vectorized 8 elems/thread
#define NB_C 512    // H*2P/(256*8)  -- vectorized 8 outs/thread
#define NB_T 2      // lambda tables

typedef __bf16 bf16x8 __attribute__((ext_vector_type(8)));
typedef float  f32x4  __attribute__((ext_vector_type(4)));
typedef unsigned short u16x8 __attribute__((ext_vector_type(8)));
typedef unsigned int   u32x4 __attribute__((ext_vector_type(4)));

__device__ __forceinline__ unsigned short f2bf(float x) {
  unsigned int u = __float_as_uint(x);
  u += 0x7FFFu + ((u >> 16) & 1u);   // round-to-nearest-even
  return (unsigned short)(u >> 16);
}
__device__ __forceinline__ float bf2f(unsigned short x) {
  return __uint_as_float((unsigned int)x << 16);
}

// ---------------------------------------------------------------------------
// Merged pack: [0,NB_U) u->bf16 cast; [NB_U,+NB_B) B_bar pack; then C pack;
// then lambda tables (lam, lam^32, lam^64). All branches are block-uniform.
// Bp (2P,H): row 2p=Re, 2p+1=Im.  Cp (H,2P): col 2p=C_re, 2p+1=-C_im.
// ---------------------------------------------------------------------------
__global__ void k_pack_all(const float* __restrict__ U, unsigned short* __restrict__ Ub,
                           const float* __restrict__ Bre, const float* __restrict__ Bim,
                           unsigned short* __restrict__ Bp,
                           const float* __restrict__ Cre, const float* __restrict__ Cim,
                           unsigned short* __restrict__ Cp,
                           const float* __restrict__ Lre, const float* __restrict__ Lim,
                           const float* __restrict__ lstep,
                           float2* __restrict__ lam, float2* __restrict__ lam32,
                           float2* __restrict__ lamK) {
  int bid = blockIdx.x, tid = threadIdx.x;
  if (bid < NB_U) {
    size_t base = ((size_t)bid * 256 + tid) * 8;
    const float4* s = (const float4*)(U + base);
    float4 v0 = s[0], v1 = s[1];
    u16x8 o;
    o[0] = f2bf(v0.x); o[1] = f2bf(v0.y); o[2] = f2bf(v0.z); o[3] = f2bf(v0.w);
    o[4] = f2bf(v1.x); o[5] = f2bf(v1.y); o[6] = f2bf(v1.z); o[7] = f2bf(v1.w);
    *(u16x8*)(Ub + base) = o;
  } else if (bid < NB_U + NB_B) {
    // 8 elems/thread; base multiple of 8, so p = base>>10 is wave-uniform
    int base = ((bid - NB_U) * 256 + tid) * 8;       // < P*H
    int p = base >> 10, h = base & 1023;
    float sv, cv;
    float step = expf(lstep[p]);
    float ar = Lre[p] * step, ai = Lim[p] * step;
    float er = expf(ar);
    sincosf(ai, &sv, &cv);
    float lr = er * cv, li = er * sv;
    float nr = lr - 1.0f, ni = li;
    float dr = Lre[p], di = Lim[p];
    float den = dr * dr + di * di;
    float cx = (nr * dr + ni * di) / den;
    float cy = (ni * dr - nr * di) / den;
    const float4* sre = (const float4*)(Bre + base);
    const float4* sim = (const float4*)(Bim + base);
    float4 r0 = sre[0], r1 = sre[1], i0 = sim[0], i1 = sim[1];
    u16x8 ore, oim;
    ore[0] = f2bf(cx * r0.x - cy * i0.x);  oim[0] = f2bf(cx * i0.x + cy * r0.x);
    ore[1] = f2bf(cx * r0.y - cy * i0.y);  oim[1] = f2bf(cx * i0.y + cy * r0.y);
    ore[2] = f2bf(cx * r0.z - cy * i0.z);  oim[2] = f2bf(cx * i0.z + cy * r0.z);
    ore[3] = f2bf(cx * r0.w - cy * i0.w);  oim[3] = f2bf(cx * i0.w + cy * r0.w);
    ore[4] = f2bf(cx * r1.x - cy * i1.x);  oim[4] = f2bf(cx * i1.x + cy * r1.x);
    ore[5] = f2bf(cx * r1.y - cy * i1.y);  oim[5] = f2bf(cx * i1.y + cy * r1.y);
    ore[6] = f2bf(cx * r1.z - cy * i1.z);  oim[6] = f2bf(cx * i1.z + cy * r1.z);
    ore[7] = f2bf(cx * r1.w - cy * i1.w);  oim[7] = f2bf(cx * i1.w + cy * r1.w);
    *(u16x8*)(Bp + (size_t)(2 * p) * H_DIM + h)     = ore;
    *(u16x8*)(Bp + (size_t)(2 * p + 1) * H_DIM + h) = oim;
  } else if (bid < NB_U + NB_B + NB_C) {
    // 8 outputs/thread: row h of Cp, cols j0..j0+7 = p0..p0+3 interleaved re/-im
    int base = ((bid - NB_U - NB_B) * 256 + tid) * 8; // < H*2P
    int h = base >> 10, j0 = base & 1023;
    int p0 = j0 >> 1;                                 // multiple of 4
    float4 cr = *(const float4*)(Cre + (size_t)h * P_DIM + p0);
    float4 ci = *(const float4*)(Cim + (size_t)h * P_DIM + p0);
    u16x8 o;
    o[0] = f2bf(cr.x); o[1] = f2bf(-ci.x);
    o[2] = f2bf(cr.y); o[3] = f2bf(-ci.y);
    o[4] = f2bf(cr.z); o[5] = f2bf(-ci.z);
    o[6] = f2bf(cr.w); o[7] = f2bf(-ci.w);
    *(u16x8*)(Cp + base) = o;
  } else {
    int p = (bid - NB_U - NB_B - NB_C) * 256 + tid;
    if (p < P_DIM) {
      double step = exp((double)lstep[p]);
      double ar = (double)Lre[p] * step, ai = (double)Lim[p] * step;
      double er = exp(ar);
      lam[p] = make_float2((float)(er * cos(ai)), (float)(er * sin(ai)));
      double ha = 32.0 * ai, hr = exp(32.0 * ar);
      lam32[p] = make_float2((float)(hr * cos(ha)), (float)(hr * sin(ha)));
      double ka = (double)CHUNK * ai, kr = exp((double)CHUNK * ar);
      lamK[p] = make_float2((float)(kr * cos(ka)), (float)(kr * sin(ka)));
    }
  }
}

// ---------------------------------------------------------------------------
// GEMM: out(M,N) = A(M,K) @ B(N,K)^T, bf16 in. 128x128 tile, BK=64, 4 waves,
// 4x4 mfma_f32_16x16x32_bf16. Grid (M/128, N/128), blockIdx.x fastest =>
// all N-tiles of an M-panel on the same XCD (A-panel fetched once per chip).
// LDS XOR swizzle (row&7) on the 8-elem column group kills the 16-way bank
// aliasing of the plain BK=64 layout.
// OUT=0: bf16 store. OUT=1: fp32 store, fused 2*acc + Dv[col]*bf2f(Ub).
// ---------------------------------------------------------------------------
template <int OUT>
__global__ void gemm_bt(const unsigned short* __restrict__ A,
                        const unsigned short* __restrict__ B,
                        void* __restrict__ Cout,
                        const unsigned short* __restrict__ Ub,
                        const float* __restrict__ Dv) {
  const int K = 1024, N = 1024;
  __shared__ unsigned short sA[128 * 64];
  __shared__ unsigned short sB[128 * 64];
  const int tid = threadIdx.x;
  const int wave = tid >> 6, lane = tid & 63;
  const int quad = lane >> 4, l16 = lane & 15;
  const int m0 = blockIdx.x * 128, n0 = blockIdx.y * 128;
  const int wm = (wave & 1) * 64, wn = (wave >> 1) * 64;

  f32x4 acc[4][4] = {};

  for (int kt = 0; kt < K; kt += 64) {
    __syncthreads();
#pragma unroll
    for (int r = 0; r < 4; ++r) {
      int s = r * 256 + tid;                   // LDS slot = staging index
      int row = s >> 3;
      int j8 = (s & 7) ^ (row & 7);            // swizzled global column-group
      const unsigned short* ga = A + (size_t)(m0 + row) * K + kt + j8 * 8;
      const unsigned short* gb = B + (size_t)(n0 + row) * K + kt + j8 * 8;
      __builtin_amdgcn_global_load_lds(
          (const __attribute__((address_space(1))) unsigned int*)ga,
          (__attribute__((address_space(3))) unsigned int*)(sA + (r * 256 + wave * 64) * 8),
          16, 0, 0);
      __builtin_amdgcn_global_load_lds(
          (const __attribute__((address_space(1))) unsigned int*)gb,
          (__attribute__((address_space(3))) unsigned int*)(sB + (r * 256 + wave * 64) * 8),
          16, 0, 0);
    }
    __syncthreads();

#pragma unroll
    for (int h = 0; h < 2; ++h) {
      bf16x8 af[4], bfr[4];
#pragma unroll
      for (int i = 0; i < 4; ++i) {
        int ra = wm + i * 16 + l16;
        af[i] = *(const bf16x8*)(sA + ra * 64 + (((h << 2) + quad) ^ (ra & 7)) * 8);
      }
#pragma unroll
      for (int j = 0; j < 4; ++j) {
        int rb = wn + j * 16 + l16;
        bfr[j] = *(const bf16x8*)(sB + rb * 64 + (((h << 2) + quad) ^ (rb & 7)) * 8);
      }
#pragma unroll
      for (int i = 0; i < 4; ++i)
#pragma unroll
        for (int j = 0; j < 4; ++j)
          acc[i][j] = __builtin_amdgcn_mfma_f32_16x16x32_bf16(af[i], bfr[j], acc[i][j], 0, 0, 0);
    }
  }

#pragma unroll
  for (int i = 0; i < 4; ++i) {
#pragma unroll
    for (int j = 0; j < 4; ++j) {
      int col = n0 + wn + j * 16 + l16;
#pragma unroll
      for (int r = 0; r < 4; ++r) {
        int row = m0 + wm + i * 16 + quad * 4 + r;
        size_t o = (size_t)row * N + col;
        float v = acc[i][j][r];
        if (OUT) {
          float u = bf2f(Ub[o]);
          ((float*)Cout)[o] = 2.0f * v + Dv[col] * u;
        } else {
          ((unsigned short*)Cout)[o] = f2bf(v);
        }
      }
    }
  }
}

// ---------------------------------------------------------------------------
// Scan pass A, t-split quarter tiles: block = (chunk, quarter) = 64 t-rows x
// 128 uint cols = 32 KB LDS, 256 threads = 2 threads/column splitting the
// t-range [0,32)/[32,64). Combine S = pB + lam^32 (x) pA via LDS.
// ---------------------------------------------------------------------------
__global__ __launch_bounds__(256) void k_scanA(const unsigned short* __restrict__ Bu,
                                               const float2* __restrict__ lam,
                                               const float2* __restrict__ lam32,
                                               float2* __restrict__ csum) {
  __shared__ unsigned int tile[CHUNK * 128];   // 32 KB
  __shared__ float2 comb[128];
  const int bid = blockIdx.x;                  // NCH*4 blocks
  const int chunk = bid >> 2, quarter = bid & 3;
  const int tid = threadIdx.x, wave = tid >> 6;
  const unsigned int* gbase =
      (const unsigned int*)Bu + (size_t)chunk * (CHUNK * 512) + quarter * 128;
  // stage 64 rows x 512 B: granule g = r*256+tid covers row g>>5, 16B-col g&31
#pragma unroll
  for (int r = 0; r < 8; ++r) {
    int g = r * 256 + tid;
    int row = g >> 5, c16 = g & 31;
    __builtin_amdgcn_global_load_lds(
        (const __attribute__((address_space(1))) unsigned int*)
            (gbase + (size_t)row * 512 + c16 * 4),
        (__attribute__((address_space(3))) unsigned int*)(tile + (r * 256 + wave * 64) * 4),
        16, 0, 0);
  }
  __syncthreads();
  const int c = tid & 127, seg = tid >> 7;     // seg is wave-uniform
  const int p = quarter * 128 + c;
  const float2 l = lam[p];
  const int t0 = seg * 32;
  float xr = 0.f, xi = 0.f;
#pragma unroll 16
  for (int t = 0; t < 32; ++t) {
    unsigned int v = tile[(t0 + t) * 128 + c];
    float br = bf2f((unsigned short)(v & 0xffffu));
    float bi = bf2f((unsigned short)(v >> 16));
    float nr = fmaf(l.x, xr, fmaf(-l.y, xi, br));
    float ni = fmaf(l.x, xi, fmaf(l.y, xr, bi));
    xr = nr; xi = ni;
  }
  if (seg == 0) comb[c] = make_float2(xr, xi);
  __syncthreads();
  if (seg == 1) {
    float2 a = comb[c];
    float2 w = lam32[p];
    float sr = xr + w.x * a.x - w.y * a.y;
    float si = xi + w.x * a.y + w.y * a.x;
    csum[(size_t)chunk * P_DIM + p] = make_float2(sr, si);
  }
}

// ---------------------------------------------------------------------------
// Carry kernel: converts csum into carry form IN PLACE, once, instead of
// every scanC block re-deriving it via an O(chunk) Horner (the chunk-255
// block's 255 serial un-pipelined L2-latency iterations were scanC's 48us
// makespan). carry[c] = lamK (x) carry[c-1] + csum[c-1], carry[0] = 0 —
// bit-identical recurrence and operation order to the old per-block Horner.
// 2 blocks x 256 threads: thread owns column p, serial over 256 chunks.
// ---------------------------------------------------------------------------
__global__ __launch_bounds__(256) void k_carry(float2* __restrict__ csum,
                                               const float2* __restrict__ lamK) {
  const int p = blockIdx.x * 256 + threadIdx.x;
  const float2 lk = lamK[p];
  float cr = 0.f, ci = 0.f;                    // carry[0]
  float2 s = csum[p];                          // original csum[0]
  csum[p] = make_float2(0.f, 0.f);
  for (int c = 1; c < NCH; ++c) {
    float nr = fmaf(lk.x, cr, fmaf(-lk.y, ci, s.x));
    float ni = fmaf(lk.x, ci, fmaf(lk.y, cr, s.y));
    cr = nr; ci = ni;                          // carry[c]
    s = csum[(size_t)c * P_DIM + p];           // original csum[c] (before overwrite)
    csum[(size_t)c * P_DIM + p] = make_float2(cr, ci);
  }
}

// ---------------------------------------------------------------------------
// Scan pass C: stages the Bu tile, reads its precomputed carry seed with ONE
// load (csum is in carry form after k_carry), seeded 64-step scan, packs bf16
// in place, wide dwordx4 store. xs aliases Bu (in-place safe: whole tile is
// in LDS + __syncthreads before any write; block regions disjoint).
// ---------------------------------------------------------------------------
__global__ __launch_bounds__(256) void k_scanC(const unsigned short* __restrict__ Bu,
                                               const float2* __restrict__ lam,
                                               const float2* __restrict__ csum,
                                               unsigned short* __restrict__ xs) {
  __shared__ unsigned int tile[CHUNK * 256];   // 64 KB
  const int bid = blockIdx.x;
  const int chunk = bid >> 1, half = bid & 1;
  const int tid = threadIdx.x, wave = tid >> 6, lane = tid & 63;
  const unsigned int* gbase =
      (const unsigned int*)(Bu + (size_t)chunk * CHUNK * N2P) + half * 256;
#pragma unroll
  for (int r = 0; r < 16; ++r) {
    int row = r * 4 + wave;
    __builtin_amdgcn_global_load_lds(
        (const __attribute__((address_space(1))) unsigned int*)
            (gbase + (size_t)row * (N2P / 2) + lane * 4),
        (__attribute__((address_space(3))) unsigned int*)(tile + row * 256),
        16, 0, 0);
  }
  // carry seed load overlaps the DMA
  const int p = half * 256 + tid;
  const float2 l = lam[p];
  const float2 seed = csum[(size_t)chunk * P_DIM + p];
  __syncthreads();
  float xr = seed.x, xi = seed.y;
#pragma unroll 16
  for (int t = 0; t < CHUNK; ++t) {
    unsigned int v = tile[t * 256 + tid];
    float br = bf2f((unsigned short)(v & 0xffffu));
    float bi = bf2f((unsigned short)(v >> 16));
    float nr = fmaf(l.x, xr, fmaf(-l.y, xi, br));
    float ni = fmaf(l.x, xi, fmaf(l.y, xr, bi));
    xr = nr; xi = ni;
    tile[t * 256 + tid] = (unsigned int)f2bf(xr) | ((unsigned int)f2bf(xi) << 16);
  }
  __syncthreads();
  unsigned int* obase = (unsigned int*)(xs + (size_t)chunk * CHUNK * N2P) + half * 256;
#pragma unroll
  for (int r = 0; r < 16; ++r) {
    int row = r * 4 + wave;
    *(u32x4*)(obase + (size_t)row * (N2P / 2) + lane * 4) =
        *(const u32x4*)(tile + row * 256 + lane * 4);
  }
}

// ---------------------------------------------------------------------------
extern "C" void kernel_launch(void* const* d_in, const int* in_sizes, int n_in,
                              void* d_out, int out_size, void* d_ws, size_t ws_size,
                              hipStream_t stream) {
  const float* U    = (const float*)d_in[0];
  const float* Lre  = (const float*)d_in[1];
  const float* Lim  = (const float*)d_in[2];
  const float* Bre  = (const float*)d_in[3];
  const float* Bim  = (const float*)d_in[4];
  const float* Cre  = (const float*)d_in[5];
  const float* Cim  = (const float*)d_in[6];
  const float* Dv   = (const float*)d_in[7];
  const float* lstp = (const float*)d_in[8];
  float* out = (float*)d_out;

  size_t off = 0;
  char* ws = (char*)d_ws;
  auto give = [&](size_t bytes) -> void* {
    void* p = ws + off;
    off += (bytes + 255) & ~(size_t)255;
    return p;
  };

  // xs aliases Bu (scanC is in-place safe; gemm1 runs after scanC).
  unsigned short* ubf  = (unsigned short*)give((size_t)L_SEQ * H_DIM * 2);  // 33.5 MB
  unsigned short* Bp   = (unsigned short*)give((size_t)N2P * H_DIM * 2);    //  2 MB
  unsigned short* Cp   = (unsigned short*)give((size_t)H_DIM * N2P * 2);    //  2 MB
  unsigned short* Bu   = (unsigned short*)give((size_t)L_SEQ * N2P * 2);    // 33.5 MB
  float2*         lam  = (float2*)give(P_DIM * sizeof(float2));
  float2*         lam32= (float2*)give(P_DIM * sizeof(float2));
  float2*         lamK = (float2*)give(P_DIM * sizeof(float2));
  float2*         csum = (float2*)give((size_t)NCH * P_DIM * sizeof(float2));
  unsigned short* xs   = Bu;   // alias (scanC is in-place safe)

  k_pack_all<<<NB_U + NB_B + NB_C + NB_T, 256, 0, stream>>>(
      U, ubf, Bre, Bim, Bp, Cre, Cim, Cp, Lre, Lim, lstp, lam, lam32, lamK);

  gemm_bt<0><<<dim3(L_SEQ / 128, N2P / 128), 256, 0, stream>>>(ubf, Bp, Bu, nullptr, nullptr);

  k_scanA<<<NCH * 4, 256, 0, stream>>>(Bu, lam, lam32, csum);
  k_carry<<<2, 256, 0, stream>>>(csum, lamK);
  k_scanC<<<NCH * 2, 256, 0, stream>>>(Bu, lam, csum, xs);

  gemm_bt<1><<<dim3(L_SEQ / 128, N2P / 128), 256, 0, stream>>>(xs, Cp, out, ubf, Dv);
}

// Round 12
// 246.375 us; speedup vs baseline: 1.0571x; 1.0046x over previous
//
#include <hip/hip_runtime.h>
#include <stdint.h>
#include <stddef.h>

#define L_SEQ 16384
#define H_DIM 1024
#define P_DIM 512
#define N2P   1024
#define CHUNK 64
#define NCH   256   // L_SEQ / CHUNK

// merged pack-kernel block ranges
#define NB_U 8192   // L*H/(256*8)
#define NB_B 256    // P*H/(256*8)   -- vectorized 8 elems/thread
#define NB_C 512    // H*2P/(256*8)  -- vectorized 8 outs/thread
#define NB_T 2      // lambda tables

typedef __bf16 bf16x8 __attribute__((ext_vector_type(8)));
typedef float  f32x4  __attribute__((ext_vector_type(4)));
typedef unsigned short u16x8 __attribute__((ext_vector_type(8)));
typedef unsigned int   u32x4 __attribute__((ext_vector_type(4)));

__device__ __forceinline__ unsigned short f2bf(float x) {
  unsigned int u = __float_as_uint(x);
  u += 0x7FFFu + ((u >> 16) & 1u);   // round-to-nearest-even
  return (unsigned short)(u >> 16);
}
__device__ __forceinline__ float bf2f(unsigned short x) {
  return __uint_as_float((unsigned int)x << 16);
}

// ---------------------------------------------------------------------------
// Merged pack: [0,NB_U) u->bf16 cast; [NB_U,+NB_B) B_bar pack; then C pack;
// then lambda tables (lam, lam^32, lam^64). All branches are block-uniform.
// Bp (2P,H): row 2p=Re, 2p+1=Im.  Cp (H,2P): col 2p=C_re, 2p+1=-C_im.
// ---------------------------------------------------------------------------
__global__ void k_pack_all(const float* __restrict__ U, unsigned short* __restrict__ Ub,
                           const float* __restrict__ Bre, const float* __restrict__ Bim,
                           unsigned short* __restrict__ Bp,
                           const float* __restrict__ Cre, const float* __restrict__ Cim,
                           unsigned short* __restrict__ Cp,
                           const float* __restrict__ Lre, const float* __restrict__ Lim,
                           const float* __restrict__ lstep,
                           float2* __restrict__ lam, float2* __restrict__ lam32,
                           float2* __restrict__ lamK) {
  int bid = blockIdx.x, tid = threadIdx.x;
  if (bid < NB_U) {
    size_t base = ((size_t)bid * 256 + tid) * 8;
    const float4* s = (const float4*)(U + base);
    float4 v0 = s[0], v1 = s[1];
    u16x8 o;
    o[0] = f2bf(v0.x); o[1] = f2bf(v0.y); o[2] = f2bf(v0.z); o[3] = f2bf(v0.w);
    o[4] = f2bf(v1.x); o[5] = f2bf(v1.y); o[6] = f2bf(v1.z); o[7] = f2bf(v1.w);
    *(u16x8*)(Ub + base) = o;
  } else if (bid < NB_U + NB_B) {
    // 8 elems/thread; base multiple of 8, so p = base>>10 is wave-uniform
    int base = ((bid - NB_U) * 256 + tid) * 8;       // < P*H
    int p = base >> 10, h = base & 1023;
    float sv, cv;
    float step = expf(lstep[p]);
    float ar = Lre[p] * step, ai = Lim[p] * step;
    float er = expf(ar);
    sincosf(ai, &sv, &cv);
    float lr = er * cv, li = er * sv;
    float nr = lr - 1.0f, ni = li;
    float dr = Lre[p], di = Lim[p];
    float den = dr * dr + di * di;
    float cx = (nr * dr + ni * di) / den;
    float cy = (ni * dr - nr * di) / den;
    const float4* sre = (const float4*)(Bre + base);
    const float4* sim = (const float4*)(Bim + base);
    float4 r0 = sre[0], r1 = sre[1], i0 = sim[0], i1 = sim[1];
    u16x8 ore, oim;
    ore[0] = f2bf(cx * r0.x - cy * i0.x);  oim[0] = f2bf(cx * i0.x + cy * r0.x);
    ore[1] = f2bf(cx * r0.y - cy * i0.y);  oim[1] = f2bf(cx * i0.y + cy * r0.y);
    ore[2] = f2bf(cx * r0.z - cy * i0.z);  oim[2] = f2bf(cx * i0.z + cy * r0.z);
    ore[3] = f2bf(cx * r0.w - cy * i0.w);  oim[3] = f2bf(cx * i0.w + cy * r0.w);
    ore[4] = f2bf(cx * r1.x - cy * i1.x);  oim[4] = f2bf(cx * i1.x + cy * r1.x);
    ore[5] = f2bf(cx * r1.y - cy * i1.y);  oim[5] = f2bf(cx * i1.y + cy * r1.y);
    ore[6] = f2bf(cx * r1.z - cy * i1.z);  oim[6] = f2bf(cx * i1.z + cy * r1.z);
    ore[7] = f2bf(cx * r1.w - cy * i1.w);  oim[7] = f2bf(cx * i1.w + cy * r1.w);
    *(u16x8*)(Bp + (size_t)(2 * p) * H_DIM + h)     = ore;
    *(u16x8*)(Bp + (size_t)(2 * p + 1) * H_DIM + h) = oim;
  } else if (bid < NB_U + NB_B + NB_C) {
    // 8 outputs/thread: row h of Cp, cols j0..j0+7 = p0..p0+3 interleaved re/-im
    int base = ((bid - NB_U - NB_B) * 256 + tid) * 8; // < H*2P
    int h = base >> 10, j0 = base & 1023;
    int p0 = j0 >> 1;                                 // multiple of 4
    float4 cr = *(const float4*)(Cre + (size_t)h * P_DIM + p0);
    float4 ci = *(const float4*)(Cim + (size_t)h * P_DIM + p0);
    u16x8 o;
    o[0] = f2bf(cr.x); o[1] = f2bf(-ci.x);
    o[2] = f2bf(cr.y); o[3] = f2bf(-ci.y);
    o[4] = f2bf(cr.z); o[5] = f2bf(-ci.z);
    o[6] = f2bf(cr.w); o[7] = f2bf(-ci.w);
    *(u16x8*)(Cp + base) = o;
  } else {
    int p = (bid - NB_U - NB_B - NB_C) * 256 + tid;
    if (p < P_DIM) {
      double step = exp((double)lstep[p]);
      double ar = (double)Lre[p] * step, ai = (double)Lim[p] * step;
      double er = exp(ar);
      lam[p] = make_float2((float)(er * cos(ai)), (float)(er * sin(ai)));
      double ha = 32.0 * ai, hr = exp(32.0 * ar);
      lam32[p] = make_float2((float)(hr * cos(ha)), (float)(hr * sin(ha)));
      double ka = (double)CHUNK * ai, kr = exp((double)CHUNK * ar);
      lamK[p] = make_float2((float)(kr * cos(ka)), (float)(kr * sin(ka)));
    }
  }
}

// ---------------------------------------------------------------------------
// GEMM: out(M,N) = A(M,K) @ B(N,K)^T, bf16 in. 128x128 tile, BK=64, 4 waves,
// 4x4 mfma_f32_16x16x32_bf16. Grid (M/128, N/128), blockIdx.x fastest =>
// all N-tiles of an M-panel on the same XCD (A-panel fetched once per chip).
// LDS XOR swizzle (row&7) on the 8-elem column group kills the 16-way bank
// aliasing of the plain BK=64 layout.
// OUT=0: bf16 store. OUT=1: fp32 store, fused 2*acc + Dv[col]*bf2f(Ub).
// ---------------------------------------------------------------------------
template <int OUT>
__global__ void gemm_bt(const unsigned short* __restrict__ A,
                        const unsigned short* __restrict__ B,
                        void* __restrict__ Cout,
                        const unsigned short* __restrict__ Ub,
                        const float* __restrict__ Dv) {
  const int K = 1024, N = 1024;
  __shared__ unsigned short sA[128 * 64];
  __shared__ unsigned short sB[128 * 64];
  const int tid = threadIdx.x;
  const int wave = tid >> 6, lane = tid & 63;
  const int quad = lane >> 4, l16 = lane & 15;
  const int m0 = blockIdx.x * 128, n0 = blockIdx.y * 128;
  const int wm = (wave & 1) * 64, wn = (wave >> 1) * 64;

  f32x4 acc[4][4] = {};

  for (int kt = 0; kt < K; kt += 64) {
    __syncthreads();
#pragma unroll
    for (int r = 0; r < 4; ++r) {
      int s = r * 256 + tid;                   // LDS slot = staging index
      int row = s >> 3;
      int j8 = (s & 7) ^ (row & 7);            // swizzled global column-group
      const unsigned short* ga = A + (size_t)(m0 + row) * K + kt + j8 * 8;
      const unsigned short* gb = B + (size_t)(n0 + row) * K + kt + j8 * 8;
      __builtin_amdgcn_global_load_lds(
          (const __attribute__((address_space(1))) unsigned int*)ga,
          (__attribute__((address_space(3))) unsigned int*)(sA + (r * 256 + wave * 64) * 8),
          16, 0, 0);
      __builtin_amdgcn_global_load_lds(
          (const __attribute__((address_space(1))) unsigned int*)gb,
          (__attribute__((address_space(3))) unsigned int*)(sB + (r * 256 + wave * 64) * 8),
          16, 0, 0);
    }
    __syncthreads();

#pragma unroll
    for (int h = 0; h < 2; ++h) {
      bf16x8 af[4], bfr[4];
#pragma unroll
      for (int i = 0; i < 4; ++i) {
        int ra = wm + i * 16 + l16;
        af[i] = *(const bf16x8*)(sA + ra * 64 + (((h << 2) + quad) ^ (ra & 7)) * 8);
      }
#pragma unroll
      for (int j = 0; j < 4; ++j) {
        int rb = wn + j * 16 + l16;
        bfr[j] = *(const bf16x8*)(sB + rb * 64 + (((h << 2) + quad) ^ (rb & 7)) * 8);
      }
#pragma unroll
      for (int i = 0; i < 4; ++i)
#pragma unroll
        for (int j = 0; j < 4; ++j)
          acc[i][j] = __builtin_amdgcn_mfma_f32_16x16x32_bf16(af[i], bfr[j], acc[i][j], 0, 0, 0);
    }
  }

#pragma unroll
  for (int i = 0; i < 4; ++i) {
#pragma unroll
    for (int j = 0; j < 4; ++j) {
      int col = n0 + wn + j * 16 + l16;
#pragma unroll
      for (int r = 0; r < 4; ++r) {
        int row = m0 + wm + i * 16 + quad * 4 + r;
        size_t o = (size_t)row * N + col;
        float v = acc[i][j][r];
        if (OUT) {
          float u = bf2f(Ub[o]);
          ((float*)Cout)[o] = 2.0f * v + Dv[col] * u;
        } else {
          ((unsigned short*)Cout)[o] = f2bf(v);
        }
      }
    }
  }
}

// ---------------------------------------------------------------------------
// Scan pass A, t-split quarter tiles: block = (chunk, quarter) = 64 t-rows x
// 128 uint cols = 32 KB LDS, 256 threads = 2 threads/column splitting the
// t-range [0,32)/[32,64). Combine S = pB + lam^32 (x) pA via LDS.
// ALSO stores the seg0 partial (pA) to csum32 -- scanC's seg1 seed needs it.
// ---------------------------------------------------------------------------
__global__ __launch_bounds__(256) void k_scanA(const unsigned short* __restrict__ Bu,
                                               const float2* __restrict__ lam,
                                               const float2* __restrict__ lam32,
                                               float2* __restrict__ csum,
                                               float2* __restrict__ csum32) {
  __shared__ unsigned int tile[CHUNK * 128];   // 32 KB
  __shared__ float2 comb[128];
  const int bid = blockIdx.x;                  // NCH*4 blocks
  const int chunk = bid >> 2, quarter = bid & 3;
  const int tid = threadIdx.x, wave = tid >> 6;
  const unsigned int* gbase =
      (const unsigned int*)Bu + (size_t)chunk * (CHUNK * 512) + quarter * 128;
  // stage 64 rows x 512 B: granule g = r*256+tid covers row g>>5, 16B-col g&31
#pragma unroll
  for (int r = 0; r < 8; ++r) {
    int g = r * 256 + tid;
    int row = g >> 5, c16 = g & 31;
    __builtin_amdgcn_global_load_lds(
        (const __attribute__((address_space(1))) unsigned int*)
            (gbase + (size_t)row * 512 + c16 * 4),
        (__attribute__((address_space(3))) unsigned int*)(tile + (r * 256 + wave * 64) * 4),
        16, 0, 0);
  }
  __syncthreads();
  const int c = tid & 127, seg = tid >> 7;     // seg is wave-uniform
  const int p = quarter * 128 + c;
  const float2 l = lam[p];
  const int t0 = seg * 32;
  float xr = 0.f, xi = 0.f;
#pragma unroll 16
  for (int t = 0; t < 32; ++t) {
    unsigned int v = tile[(t0 + t) * 128 + c];
    float br = bf2f((unsigned short)(v & 0xffffu));
    float bi = bf2f((unsigned short)(v >> 16));
    float nr = fmaf(l.x, xr, fmaf(-l.y, xi, br));
    float ni = fmaf(l.x, xi, fmaf(l.y, xr, bi));
    xr = nr; xi = ni;
  }
  if (seg == 0) {
    comb[c] = make_float2(xr, xi);
    csum32[(size_t)chunk * P_DIM + p] = make_float2(xr, xi);
  }
  __syncthreads();
  if (seg == 1) {
    float2 a = comb[c];
    float2 w = lam32[p];
    float sr = xr + w.x * a.x - w.y * a.y;
    float si = xi + w.x * a.y + w.y * a.x;
    csum[(size_t)chunk * P_DIM + p] = make_float2(sr, si);
  }
}

// ---------------------------------------------------------------------------
// Carry kernel: converts csum into carry form IN PLACE, once (O(NCH) total
// instead of every scanC block re-deriving an O(chunk) Horner — R11: -9.5us).
// carry[c] = lamK (x) carry[c-1] + csum[c-1], carry[0] = 0.
// ---------------------------------------------------------------------------
__global__ __launch_bounds__(256) void k_carry(float2* __restrict__ csum,
                                               const float2* __restrict__ lamK) {
  const int p = blockIdx.x * 256 + threadIdx.x;
  const float2 lk = lamK[p];
  float cr = 0.f, ci = 0.f;                    // carry[0]
  float2 s = csum[p];                          // original csum[0]
  csum[p] = make_float2(0.f, 0.f);
  for (int c = 1; c < NCH; ++c) {
    float nr = fmaf(lk.x, cr, fmaf(-lk.y, ci, s.x));
    float ni = fmaf(lk.x, ci, fmaf(lk.y, cr, s.y));
    cr = nr; ci = ni;                          // carry[c]
    s = csum[(size_t)c * P_DIM + p];           // original csum[c] (before overwrite)
    csum[(size_t)c * P_DIM + p] = make_float2(cr, ci);
  }
}

// ---------------------------------------------------------------------------
// Scan pass C, t-split quarter tiles (the scanA mechanism: chain 64->32 +
// occupancy 2->4 blocks/CU). seg0 scans t[0,32) seeded with carry; seg1
// scans t[32,64) seeded with x[31] = lam32 (x) carry + csum32. Both segs
// pack bf16 into disjoint tile rows; granule-linear dwordx4 store.
// xs aliases Bu: in-place safe (region in LDS + sync before write).
// ---------------------------------------------------------------------------
__global__ __launch_bounds__(256) void k_scanC(const unsigned short* __restrict__ Bu,
                                               const float2* __restrict__ lam,
                                               const float2* __restrict__ lam32,
                                               const float2* __restrict__ csum,
                                               const float2* __restrict__ csum32,
                                               unsigned short* __restrict__ xs) {
  __shared__ unsigned int tile[CHUNK * 128];   // 32 KB
  const int bid = blockIdx.x;                  // NCH*4 blocks
  const int chunk = bid >> 2, quarter = bid & 3;
  const int tid = threadIdx.x, wave = tid >> 6;
  const unsigned int* gbase =
      (const unsigned int*)Bu + (size_t)chunk * (CHUNK * 512) + quarter * 128;
#pragma unroll
  for (int r = 0; r < 8; ++r) {
    int g = r * 256 + tid;
    int row = g >> 5, c16 = g & 31;
    __builtin_amdgcn_global_load_lds(
        (const __attribute__((address_space(1))) unsigned int*)
            (gbase + (size_t)row * 512 + c16 * 4),
        (__attribute__((address_space(3))) unsigned int*)(tile + (r * 256 + wave * 64) * 4),
        16, 0, 0);
  }
  // seed loads overlap the DMA
  const int c = tid & 127, seg = tid >> 7;     // seg is wave-uniform
  const int p = quarter * 128 + c;
  const float2 l = lam[p];
  const float2 cy = csum[(size_t)chunk * P_DIM + p];   // carry
  float xr, xi;
  if (seg == 0) {
    xr = cy.x; xi = cy.y;
  } else {
    float2 w = lam32[p];
    float2 s32 = csum32[(size_t)chunk * P_DIM + p];
    xr = fmaf(w.x, cy.x, fmaf(-w.y, cy.y, s32.x));     // x[31]
    xi = fmaf(w.x, cy.y, fmaf(w.y, cy.x, s32.y));
  }
  __syncthreads();
  const int t0 = seg * 32;
#pragma unroll 16
  for (int t = 0; t < 32; ++t) {
    unsigned int v = tile[(t0 + t) * 128 + c];
    float br = bf2f((unsigned short)(v & 0xffffu));
    float bi = bf2f((unsigned short)(v >> 16));
    float nr = fmaf(l.x, xr, fmaf(-l.y, xi, br));
    float ni = fmaf(l.x, xi, fmaf(l.y, xr, bi));
    xr = nr; xi = ni;
    tile[(t0 + t) * 128 + c] = (unsigned int)f2bf(xr) | ((unsigned int)f2bf(xi) << 16);
  }
  __syncthreads();
  unsigned int* ob = (unsigned int*)xs + (size_t)chunk * (CHUNK * 512) + quarter * 128;
#pragma unroll
  for (int r = 0; r < 8; ++r) {
    int g = r * 256 + tid;
    int row = g >> 5, c16 = g & 31;
    *(u32x4*)(ob + (size_t)row * 512 + c16 * 4) = *(const u32x4*)(tile + g * 4);
  }
}

// ---------------------------------------------------------------------------
extern "C" void kernel_launch(void* const* d_in, const int* in_sizes, int n_in,
                              void* d_out, int out_size, void* d_ws, size_t ws_size,
                              hipStream_t stream) {
  const float* U    = (const float*)d_in[0];
  const float* Lre  = (const float*)d_in[1];
  const float* Lim  = (const float*)d_in[2];
  const float* Bre  = (const float*)d_in[3];
  const float* Bim  = (const float*)d_in[4];
  const float* Cre  = (const float*)d_in[5];
  const float* Cim  = (const float*)d_in[6];
  const float* Dv   = (const float*)d_in[7];
  const float* lstp = (const float*)d_in[8];
  float* out = (float*)d_out;

  size_t off = 0;
  char* ws = (char*)d_ws;
  auto give = [&](size_t bytes) -> void* {
    void* p = ws + off;
    off += (bytes + 255) & ~(size_t)255;
    return p;
  };

  // xs aliases Bu (scanC is in-place safe; gemm1 runs after scanC).
  unsigned short* ubf  = (unsigned short*)give((size_t)L_SEQ * H_DIM * 2);  // 33.5 MB
  unsigned short* Bp   = (unsigned short*)give((size_t)N2P * H_DIM * 2);    //  2 MB
  unsigned short* Cp   = (unsigned short*)give((size_t)H_DIM * N2P * 2);    //  2 MB
  unsigned short* Bu   = (unsigned short*)give((size_t)L_SEQ * N2P * 2);    // 33.5 MB
  float2*         lam  = (float2*)give(P_DIM * sizeof(float2));
  float2*         lam32= (float2*)give(P_DIM * sizeof(float2));
  float2*         lamK = (float2*)give(P_DIM * sizeof(float2));
  float2*         csum = (float2*)give((size_t)NCH * P_DIM * sizeof(float2));
  float2*         csum32 = (float2*)give((size_t)NCH * P_DIM * sizeof(float2));
  unsigned short* xs   = Bu;   // alias (scanC is in-place safe)

  k_pack_all<<<NB_U + NB_B + NB_C + NB_T, 256, 0, stream>>>(
      U, ubf, Bre, Bim, Bp, Cre, Cim, Cp, Lre, Lim, lstp, lam, lam32, lamK);

  gemm_bt<0><<<dim3(L_SEQ / 128, N2P / 128), 256, 0, stream>>>(ubf, Bp, Bu, nullptr, nullptr);

  k_scanA<<<NCH * 4, 256, 0, stream>>>(Bu, lam, lam32, csum, csum32);
  k_carry<<<2, 256, 0, stream>>>(csum, lamK);
  k_scanC<<<NCH * 4, 256, 0, stream>>>(Bu, lam, lam32, csum, csum32, xs);

  gemm_bt<1><<<dim3(L_SEQ / 128, N2P / 128), 256, 0, stream>>>(xs, Cp, out, ubf, Dv);
}